// Round 10
// baseline (245.948 us; speedup 1.0000x reference)
//
#include <hip/hip_runtime.h>

#define NSEG 15872
#define DD 129
#define HH 128
#define NTILE (NSEG / 16)  // 992 node tiles

typedef __attribute__((ext_vector_type(8))) short s16x8;
typedef __attribute__((ext_vector_type(4))) float f32x4;

__device__ __forceinline__ unsigned short f2bf(float x) {
  union { float f; unsigned u; } c; c.f = x;
  unsigned r = c.u + 0x7FFFu + ((c.u >> 16) & 1u);
  return (unsigned short)(r >> 16);
}

// ---------------------------------------------------------------------------
// Generic MFMA B-fragment packer: out[(g*N + n)*8 + i] =
//   bf16(W[(rowBase + g*8+i)*ld + n])  (0 outside kLimit/ncols)
// ---------------------------------------------------------------------------
__device__ __forceinline__ void packB(short* out, int idx, const float* W,
                                      int N, int ld, int ncols, int kLimit,
                                      int rowBase) {
  const int i = idx & 7;
  const int n = (idx >> 3) % N;
  const int g = idx / (8 * N);
  const int row = g * 8 + i;
  float v = 0.f;
  if (row < kLimit && n < ncols) v = W[(long)(rowBase + row) * ld + n];
  out[idx] = (short)f2bf(v);
}

// W2 packer with K-permutation: packed K-position k' holds original W2 row
// k = (k'&7)*16 + (k'>>3), matching the bounce layout (k' = n16*8+nf).
__device__ __forceinline__ void packB2perm(short* out, int idx, const float* W) {
  const int i = idx & 7;
  const int n = (idx >> 3) & 127;
  const int g = idx >> 10;
  const int kp = g * 8 + i;
  const int k = ((kp & 7) << 4) + (kp >> 3);
  out[idx] = (short)f2bf(W[(long)k * HH + n]);
}

// ---------------------------------------------------------------------------
// prep_all: block 0 = scan + counting-sort-by-size (for segment pairing);
// blocks 1..632 = weight packing; rest = bf16 TAB.
// ---------------------------------------------------------------------------
#define PACK_IDS 161792  // 40960+32768+36864+40960+10240
#define TAB_IDS (NSEG * 160)
__global__ __launch_bounds__(256) void prep_all_kernel(
    const int* __restrict__ sizes, int* __restrict__ offs,
    int* __restrict__ sorted,
    const float* __restrict__ interp, unsigned short* __restrict__ tab,
    const float* __restrict__ W1b0, const float* __restrict__ W1b1,
    const float* __restrict__ W2b0, const float* __restrict__ W2b1,
    const float* __restrict__ Wob0, const float* __restrict__ Wob1,
    const float* __restrict__ fW1, short* __restrict__ PB1,
    short* __restrict__ PB2, short* __restrict__ PWo,
    short* __restrict__ PW1m, short* __restrict__ PfW1) {
  if (blockIdx.x == 0) {
    __shared__ int sums[256];
    __shared__ int pref[256];
    __shared__ int bins[1024];
    const int t = threadIdx.x;
    const int chunk = (NSEG + 255) >> 8;
    const int s0 = t * chunk, s1 = min(s0 + chunk, NSEG);
    int s = 0;
    for (int i = s0; i < s1; ++i) s += sizes[i];
    sums[t] = s;
    __syncthreads();
    if (t == 0) { int a = 0; for (int i = 0; i < 256; ++i) { pref[i] = a; a += sums[i]; } }
    __syncthreads();
    int a = pref[t];
    for (int i = s0; i < s1; ++i) { offs[i] = a; a += sizes[i]; }
    if (t == 255) offs[NSEG] = a;
    // counting sort of segment ids by size (ascending) -> sorted[]
    for (int i = t; i < 1024; i += 256) bins[i] = 0;
    __syncthreads();
    for (int i = t; i < NSEG; i += 256) {
      int sz = sizes[i]; sz = sz < 0 ? 0 : (sz > 1023 ? 1023 : sz);
      atomicAdd(&bins[sz], 1);
    }
    __syncthreads();
    if (t == 0) {
      int acc = 0;
      for (int i = 0; i < 1024; ++i) { int c = bins[i]; bins[i] = acc; acc += c; }
    }
    __syncthreads();
    for (int i = t; i < NSEG; i += 256) {
      int sz = sizes[i]; sz = sz < 0 ? 0 : (sz > 1023 ? 1023 : sz);
      int pos = atomicAdd(&bins[sz], 1);
      sorted[pos] = i;
    }
    return;
  }
  int id = (blockIdx.x - 1) * 256 + threadIdx.x;
  if (id < PACK_IDS) {
    if (id < 40960) {  // W1 neighbor half, K 129->160, N 128
      packB(PB1 + (id / 20480) * 20480, id % 20480, (id < 20480) ? W1b0 : W1b1,
            128, 128, 128, 129, 0);
      return;
    }
    id -= 40960;
    if (id < 32768) {  // W2 (K-permuted), K 128, N 128
      packB2perm(PB2 + (id / 16384) * 16384, id % 16384,
                 (id < 16384) ? W2b0 : W2b1);
      return;
    }
    id -= 32768;
    if (id < 36864) {  // Wo, K 128, N 129->144
      packB(PWo + (id / 18432) * 18432, id % 18432, (id < 18432) ? Wob0 : Wob1,
            144, 129, 129, 128, 0);
      return;
    }
    id -= 36864;
    if (id < 40960) {  // W1 main half (rows 129..257), K 129->160, N 128
      packB(PW1m + (id / 20480) * 20480, id % 20480, (id < 20480) ? W1b0 : W1b1,
            128, 128, 128, 129, 129);
      return;
    }
    id -= 40960;
    packB(PfW1, id, fW1, 64, 64, 64, 129, 0);  // fW1 K 129->160, N 64
    return;
  }
  id -= PACK_IDS;
  if (id < TAB_IDS) {
    const int n = id / 160, k = id - n * 160;
    tab[id] = (k < DD) ? f2bf(interp[(long)n * DD + k]) : (unsigned short)0;
  }
}

// ---------------------------------------------------------------------------
// HM = b1 + tab @ W1main  (dense MFMA over 16-node tiles; block-0 only)
// ---------------------------------------------------------------------------
__global__ __launch_bounds__(256) void hmprep_kernel(
    const unsigned short* __restrict__ tab, const short* __restrict__ PW1m,
    const float* __restrict__ b1, float* __restrict__ Hm) {
  const int lane = threadIdx.x & 63, w = threadIdx.x >> 6;
  const int lk = lane >> 4, n16 = lane & 15;
  const int tile = blockIdx.x * 4 + w;
  const unsigned short* arow = tab + (long)(tile * 16 + n16) * 160;
  s16x8 A[5];
#pragma unroll
  for (int ks = 0; ks < 5; ++ks) A[ks] = *(const s16x8*)(arow + ks * 32 + lk * 8);
  f32x4 C[8];
#pragma unroll
  for (int nf = 0; nf < 8; ++nf) C[nf] = (f32x4){0.f, 0.f, 0.f, 0.f};
#pragma unroll
  for (int ks = 0; ks < 5; ++ks)
#pragma unroll
    for (int nf = 0; nf < 8; ++nf) {
      const s16x8 b = *(const s16x8*)(PW1m + (((ks * 4 + lk) * 128) + nf * 16 + n16) * 8);
      C[nf] = __builtin_amdgcn_mfma_f32_16x16x32_bf16(A[ks], b, C[nf], 0, 0, 0);
    }
#pragma unroll
  for (int nf = 0; nf < 8; ++nf) {
    const float bv = b1[nf * 16 + n16];
#pragma unroll
    for (int r = 0; r < 4; ++r)
      Hm[(long)(tile * 16 + lk * 4 + r) * HH + nf * 16 + n16] = C[nf][r] + bv;
  }
}

// row within a packed pair -> edge index (rows < sLo from Lo segment, rest
// from Hi; overflow rows clamp to Hi's last edge — benign under max)
__device__ __forceinline__ int pairEdge(int row, int oLo, int sLo, int oHi,
                                        int sHi) {
  int e = (row < sLo) ? (oLo + row) : (oHi + row - sLo);
  if (row >= sLo + sHi) e = oHi + sHi - 1;
  return e;
}

// ---------------------------------------------------------------------------
// edge_kernel: fused GEMM1 + GEMM2 + segment-max over PACKED segment pairs.
// Pairing (smallest+largest size) makes every pair sum to ~32 edges -> zero
// tile padding (15872 tiles vs 23552 segment-aligned: the R9 1.48x waste).
// Two pairs per wave in lockstep (each LDS B-frag read feeds two MFMAs).
// Bounce tile uses K-permuted layout (b128 writes); PB2 rows permuted.
// ---------------------------------------------------------------------------
__global__ __launch_bounds__(512, 2) void edge_kernel(
    const unsigned short* __restrict__ tab, const short* __restrict__ PB1,
    const short* __restrict__ PB2, const float* __restrict__ W1,
    const float* __restrict__ Hm, const float* __restrict__ iou,
    const int* __restrict__ nbrIdx, const int* __restrict__ offs,
    const int* __restrict__ sorted, const float* __restrict__ b2,
    unsigned short* __restrict__ pooled) {
  extern __shared__ __align__(16) char smem[];
  short* Bs1 = (short*)smem;                  // 40960 B
  short* Bs2 = (short*)(smem + 40960);        // 32768 B
  short* stAll = (short*)(smem + 73728);      // 8 waves * 2 * 16*136*2 B
  {
    const f32x4* s1 = (const f32x4*)PB1;
    f32x4* d1 = (f32x4*)Bs1;
    for (int i = threadIdx.x; i < 2560; i += 512) d1[i] = s1[i];
    const f32x4* s2 = (const f32x4*)PB2;
    f32x4* d2 = (f32x4*)Bs2;
    for (int i = threadIdx.x; i < 2048; i += 512) d2[i] = s2[i];
  }
  __syncthreads();

  const int lane = threadIdx.x & 63;
  const int w = threadIdx.x >> 6;
  const int lk = lane >> 4, n16 = lane & 15;
  short* stA = stAll + w * 2 * (16 * 136);
  short* stB = stA + 16 * 136;

  float wv[8], bv[8];
#pragma unroll
  for (int nf = 0; nf < 8; ++nf) {
    wv[nf] = W1[258 * HH + nf * 16 + n16];
    bv[nf] = b2[nf * 16 + n16];
  }

  const int wid = (blockIdx.x << 3) + w;
  const int nw = gridDim.x << 3;
  const int npairs = NSEG >> 1;

  for (int p = wid; p < npairs; p += 2 * nw) {
    const int pA = p;
    int pB = p + nw;
    if (pB >= npairs) pB = pA;  // duplicate slot (benign)
    const int segLoA = sorted[pA], segHiA = sorted[NSEG - 1 - pA];
    const int segLoB = sorted[pB], segHiB = sorted[NSEG - 1 - pB];
    const int oLoA = offs[segLoA], sLoA = offs[segLoA + 1] - oLoA;
    const int oHiA = offs[segHiA], sHiA = offs[segHiA + 1] - oHiA;
    const int oLoB = offs[segLoB], sLoB = offs[segLoB + 1] - oLoB;
    const int oHiB = offs[segHiB], sHiB = offs[segHiB + 1] - oHiB;
    const int nt = (max(sLoA + sHiA, sLoB + sHiB) + 15) >> 4;

    float hmLoA[8], hmHiA[8], hmLoB[8], hmHiB[8];
    float pmLoA[8], pmHiA[8], pmLoB[8], pmHiB[8];
#pragma unroll
    for (int nf = 0; nf < 8; ++nf) {
      const int col = nf * 16 + n16;
      hmLoA[nf] = Hm[(long)segLoA * HH + col];
      hmHiA[nf] = Hm[(long)segHiA * HH + col];
      hmLoB[nf] = Hm[(long)segLoB * HH + col];
      hmHiB[nf] = Hm[(long)segHiB * HH + col];
      pmLoA[nf] = 0.f; pmHiA[nf] = 0.f; pmLoB[nf] = 0.f; pmHiB[nf] = 0.f;
    }

    for (int t = 0; t < nt; ++t) {
      const int row16 = (t << 4) + n16;
      const int eA = pairEdge(row16, oLoA, sLoA, oHiA, sHiA);
      const int eB = pairEdge(row16, oLoB, sLoB, oHiB, sHiB);
      const unsigned short* rA = tab + (long)nbrIdx[eA] * 160;
      const unsigned short* rB = tab + (long)nbrIdx[eB] * 160;
      s16x8 AA[5], AB[5];
#pragma unroll
      for (int ks = 0; ks < 5; ++ks) {
        AA[ks] = *(const s16x8*)(rA + ks * 32 + lk * 8);
        AB[ks] = *(const s16x8*)(rB + ks * 32 + lk * 8);
      }
      float ioA[4], ioB[4];
#pragma unroll
      for (int r = 0; r < 4; ++r) {
        const int row = (t << 4) + lk * 4 + r;
        ioA[r] = iou[pairEdge(row, oLoA, sLoA, oHiA, sHiA)];
        ioB[r] = iou[pairEdge(row, oLoB, sLoB, oHiB, sHiB)];
      }
      // GEMM1 (B read once, two MFMAs)
      f32x4 C1A[8], C1B[8];
#pragma unroll
      for (int nf = 0; nf < 8; ++nf) {
        C1A[nf] = (f32x4){0.f, 0.f, 0.f, 0.f};
        C1B[nf] = (f32x4){0.f, 0.f, 0.f, 0.f};
      }
#pragma unroll
      for (int ks = 0; ks < 5; ++ks)
#pragma unroll
        for (int nf = 0; nf < 8; ++nf) {
          const s16x8 b = *(const s16x8*)(Bs1 + (((ks * 4 + lk) * 128) + nf * 16 + n16) * 8);
          C1A[nf] = __builtin_amdgcn_mfma_f32_16x16x32_bf16(AA[ks], b, C1A[nf], 0, 0, 0);
          C1B[nf] = __builtin_amdgcn_mfma_f32_16x16x32_bf16(AB[ks], b, C1B[nf], 0, 0, 0);
        }
      // bounce: 8 nf-values per row -> one b128 (K-permuted layout);
      // Hm selected per row by segment membership
#pragma unroll
      for (int r = 0; r < 4; ++r) {
        const int row = (t << 4) + lk * 4 + r;
        const bool lA = row < sLoA, lB = row < sLoB;
        s16x8 oA, oB;
#pragma unroll
        for (int nf = 0; nf < 8; ++nf) {
          const float hA = lA ? hmLoA[nf] : hmHiA[nf];
          const float hB = lB ? hmLoB[nf] : hmHiB[nf];
          oA[nf] = (short)f2bf(fmaxf(C1A[nf][r] + ioA[r] * wv[nf] + hA, 0.f));
          oB[nf] = (short)f2bf(fmaxf(C1B[nf][r] + ioB[r] * wv[nf] + hB, 0.f));
        }
        *(s16x8*)(stA + (lk * 4 + r) * 136 + n16 * 8) = oA;
        *(s16x8*)(stB + (lk * 4 + r) * 136 + n16 * 8) = oB;
      }
      // GEMM2 A-frags from LDS (row=n16 edge, k'=ks*32+lk*8)
      s16x8 A2A[4], A2B[4];
#pragma unroll
      for (int ks = 0; ks < 4; ++ks) {
        A2A[ks] = *(const s16x8*)(stA + n16 * 136 + ks * 32 + lk * 8);
        A2B[ks] = *(const s16x8*)(stB + n16 * 136 + ks * 32 + lk * 8);
      }
      f32x4 C2A[8], C2B[8];
#pragma unroll
      for (int nf = 0; nf < 8; ++nf) {
        C2A[nf] = (f32x4){0.f, 0.f, 0.f, 0.f};
        C2B[nf] = (f32x4){0.f, 0.f, 0.f, 0.f};
      }
#pragma unroll
      for (int ks = 0; ks < 4; ++ks)
#pragma unroll
        for (int nf = 0; nf < 8; ++nf) {
          const s16x8 b = *(const s16x8*)(Bs2 + (((ks * 4 + lk) * 128) + nf * 16 + n16) * 8);
          C2A[nf] = __builtin_amdgcn_mfma_f32_16x16x32_bf16(A2A[ks], b, C2A[nf], 0, 0, 0);
          C2B[nf] = __builtin_amdgcn_mfma_f32_16x16x32_bf16(A2B[ks], b, C2B[nf], 0, 0, 0);
        }
      // per-row segment-split max update
#pragma unroll
      for (int r = 0; r < 4; ++r) {
        const int row = (t << 4) + lk * 4 + r;
        const bool lA = row < sLoA, lB = row < sLoB;
#pragma unroll
        for (int nf = 0; nf < 8; ++nf) {
          const float vA = C2A[nf][r] + bv[nf];
          const float vB = C2B[nf][r] + bv[nf];
          if (lA) pmLoA[nf] = fmaxf(pmLoA[nf], vA);
          else    pmHiA[nf] = fmaxf(pmHiA[nf], vA);
          if (lB) pmLoB[nf] = fmaxf(pmLoB[nf], vB);
          else    pmHiB[nf] = fmaxf(pmHiB[nf], vB);
        }
      }
    }
#pragma unroll
    for (int nf = 0; nf < 8; ++nf) {
      float a = pmLoA[nf], b = pmHiA[nf], c = pmLoB[nf], d = pmHiB[nf];
      a = fmaxf(a, __shfl_xor(a, 16, 64)); a = fmaxf(a, __shfl_xor(a, 32, 64));
      b = fmaxf(b, __shfl_xor(b, 16, 64)); b = fmaxf(b, __shfl_xor(b, 32, 64));
      c = fmaxf(c, __shfl_xor(c, 16, 64)); c = fmaxf(c, __shfl_xor(c, 32, 64));
      d = fmaxf(d, __shfl_xor(d, 16, 64)); d = fmaxf(d, __shfl_xor(d, 32, 64));
      pmLoA[nf] = a; pmHiA[nf] = b; pmLoB[nf] = c; pmHiB[nf] = d;
    }
    if (lane < 16) {
#pragma unroll
      for (int nf = 0; nf < 8; ++nf) {
        const int col = nf * 16 + n16;
        pooled[(long)segLoA * HH + col] = f2bf(pmLoA[nf]);
        pooled[(long)segHiA * HH + col] = f2bf(pmHiA[nf]);
        pooled[(long)segLoB * HH + col] = f2bf(pmLoB[nf]);
        pooled[(long)segHiB * HH + col] = f2bf(pmHiB[nf]);
      }
    }
  }
}

// ---------------------------------------------------------------------------
// resout: RES = resIn + bo + pooled @ Wo (MFMA). Then, via a bf16 LDS bounce
// of the result row:
//   NEXT=1: write resOut fp32 + TAB bf16 and compute HM_next = b1n + res@W1m.
//   NEXT=0: fused final head out = relu(res@fW1+fb1)@fW2 + fb2.
// ---------------------------------------------------------------------------
template <int NEXT>
__global__ __launch_bounds__(256) void resout_kernel(
    const unsigned short* __restrict__ pooled, const short* __restrict__ PWo,
    const float* __restrict__ bo, const float* __restrict__ resIn,
    float* __restrict__ resOut, unsigned short* __restrict__ tab,
    const short* __restrict__ PW1mN, const float* __restrict__ b1n,
    float* __restrict__ HmOut,
    const short* __restrict__ PfW1, const float* __restrict__ fb1,
    const float* __restrict__ fW2, const float* __restrict__ fb2,
    float* __restrict__ outFinal) {
  __shared__ short stS[4][16 * 168];
  const int lane = threadIdx.x & 63, w = threadIdx.x >> 6;
  const int lk = lane >> 4, n16 = lane & 15;
  short* st = stS[w];

  // zero the k-pad cols 129..160 once (A-frag reads touch up to col 159)
  {
    const int row = lane >> 2, c0 = 129 + (lane & 3) * 8;
#pragma unroll
    for (int i = 0; i < 8; ++i) st[row * 168 + c0 + i] = 0;
  }

  const int tile = blockIdx.x * 4 + w;
  const unsigned short* arow = pooled + (long)(tile * 16 + n16) * HH;
  s16x8 A[4];
#pragma unroll
  for (int ks = 0; ks < 4; ++ks) A[ks] = *(const s16x8*)(arow + ks * 32 + lk * 8);
  f32x4 C[9];
#pragma unroll
  for (int nf = 0; nf < 9; ++nf) C[nf] = (f32x4){0.f, 0.f, 0.f, 0.f};
#pragma unroll
  for (int ks = 0; ks < 4; ++ks)
#pragma unroll
    for (int nf = 0; nf < 9; ++nf) {
      const s16x8 b = *(const s16x8*)(PWo + (((ks * 4 + lk) * 144) + nf * 16 + n16) * 8);
      C[nf] = __builtin_amdgcn_mfma_f32_16x16x32_bf16(A[ks], b, C[nf], 0, 0, 0);
    }

#pragma unroll
  for (int nf = 0; nf < 8; ++nf) {
    const int col = nf * 16 + n16;
    const float bov = bo[col];
#pragma unroll
    for (int r = 0; r < 4; ++r) {
      const int row = lk * 4 + r;
      const long node = tile * 16 + row;
      const float res = resIn[node * DD + col] + bov + C[nf][r];
      if (NEXT) {
        resOut[node * DD + col] = res;
        tab[node * 160 + col] = f2bf(res);
      }
      st[row * 168 + col] = (short)f2bf(res);
    }
  }
  if (n16 == 0) {
#pragma unroll
    for (int r = 0; r < 4; ++r) {
      const int row = lk * 4 + r;
      const long node = tile * 16 + row;
      const float res = resIn[node * DD + 128] + bo[128] + C[8][r];
      if (NEXT) {
        resOut[node * DD + 128] = res;
        tab[node * 160 + 128] = f2bf(res);
      }
      st[row * 168 + 128] = (short)f2bf(res);
    }
  }

  // A-frags of res from the bounce tile (row=n16 node, k=ks*32+lk*8, pad 0)
  s16x8 A5[5];
#pragma unroll
  for (int ks = 0; ks < 5; ++ks)
    A5[ks] = *(const s16x8*)(st + n16 * 168 + ks * 32 + lk * 8);

  if (NEXT) {
    f32x4 H[8];
#pragma unroll
    for (int nf = 0; nf < 8; ++nf) H[nf] = (f32x4){0.f, 0.f, 0.f, 0.f};
#pragma unroll
    for (int ks = 0; ks < 5; ++ks)
#pragma unroll
      for (int nf = 0; nf < 8; ++nf) {
        const s16x8 b = *(const s16x8*)(PW1mN + (((ks * 4 + lk) * 128) + nf * 16 + n16) * 8);
        H[nf] = __builtin_amdgcn_mfma_f32_16x16x32_bf16(A5[ks], b, H[nf], 0, 0, 0);
      }
#pragma unroll
    for (int nf = 0; nf < 8; ++nf) {
      const float bv = b1n[nf * 16 + n16];
#pragma unroll
      for (int r = 0; r < 4; ++r)
        HmOut[(long)(tile * 16 + lk * 4 + r) * HH + nf * 16 + n16] = H[nf][r] + bv;
    }
  } else {
    f32x4 Ch[4];
#pragma unroll
    for (int nf = 0; nf < 4; ++nf) Ch[nf] = (f32x4){0.f, 0.f, 0.f, 0.f};
#pragma unroll
    for (int ks = 0; ks < 5; ++ks)
#pragma unroll
      for (int nf = 0; nf < 4; ++nf) {
        const s16x8 b = *(const s16x8*)(PfW1 + (((ks * 4 + lk) * 64) + nf * 16 + n16) * 8);
        Ch[nf] = __builtin_amdgcn_mfma_f32_16x16x32_bf16(A5[ks], b, Ch[nf], 0, 0, 0);
      }
    float b1v[4], w2v[4];
#pragma unroll
    for (int nf = 0; nf < 4; ++nf) {
      b1v[nf] = fb1[nf * 16 + n16];
      w2v[nf] = fW2[nf * 16 + n16];
    }
#pragma unroll
    for (int r = 0; r < 4; ++r) {
      float s = 0.f;
#pragma unroll
      for (int nf = 0; nf < 4; ++nf)
        s += fmaxf(Ch[nf][r] + b1v[nf], 0.f) * w2v[nf];
      s += __shfl_xor(s, 1, 64);
      s += __shfl_xor(s, 2, 64);
      s += __shfl_xor(s, 4, 64);
      s += __shfl_xor(s, 8, 64);
      if (n16 == 0) outFinal[tile * 16 + lk * 4 + r] = s + fb2[0];
    }
  }
}

// ---------------------------------------------------------------------------
extern "C" void kernel_launch(void* const* d_in, const int* in_sizes, int n_in,
                              void* d_out, int out_size, void* d_ws, size_t ws_size,
                              hipStream_t stream) {
  const float* interp  = (const float*)d_in[0];
  const float* addInfo = (const float*)d_in[1];
  const int* sizes     = (const int*)d_in[2];
  const int* nbrIdx    = (const int*)d_in[3];
  const float* b0W1 = (const float*)d_in[5];
  const float* b0b1 = (const float*)d_in[6];
  const float* b0W2 = (const float*)d_in[7];
  const float* b0b2 = (const float*)d_in[8];
  const float* b0Wo = (const float*)d_in[9];
  const float* b0bo = (const float*)d_in[10];
  const float* b1W1 = (const float*)d_in[11];
  const float* b1b1 = (const float*)d_in[12];
  const float* b1W2 = (const float*)d_in[13];
  const float* b1b2 = (const float*)d_in[14];
  const float* b1Wo = (const float*)d_in[15];
  const float* b1bo = (const float*)d_in[16];
  const float* fW1  = (const float*)d_in[17];
  const float* fb1  = (const float*)d_in[18];
  const float* fW2  = (const float*)d_in[19];
  const float* fb2  = (const float*)d_in[20];

  char* ws = (char*)d_ws;
  int*            offs  = (int*)(ws + 0);                    // 65536
  short*          PB1   = (short*)(ws + 65536);              // 81920
  short*          PB2   = (short*)(ws + 147456);             // 65536
  short*          PWo   = (short*)(ws + 212992);             // 73728
  short*          PW1m  = (short*)(ws + 286720);             // 81920
  short*          PfW1  = (short*)(ws + 368640);             // 20480 -> pad
  unsigned short* TAB   = (unsigned short*)(ws + 393216);    // N*160*2
  float*          HM    = (float*)(ws + 5472256);            // N*128*4
  unsigned short* POOLED= (unsigned short*)(ws + 13598720);  // N*128*2
  float*          RES   = (float*)(ws + 17661952);           // N*129*4
  int*            SORTED= (int*)(ws + 25851904);             // N*4

  const int prep_blocks = 1 + (PACK_IDS / 256) + (TAB_IDS / 256);  // 10553
  prep_all_kernel<<<prep_blocks, 256, 0, stream>>>(
      sizes, offs, SORTED, interp, TAB, b0W1, b1W1, b0W2, b1W2, b0Wo, b1Wo,
      fW1, PB1, PB2, PWo, PW1m, PfW1);

  const size_t e_lds = 40960 + 32768 + 8 * 2 * 16 * 136 * 2;  // 143360

  // ---- block 0 ----
  hmprep_kernel<<<NTILE / 4, 256, 0, stream>>>(TAB, PW1m, b0b1, HM);
  edge_kernel<<<256, 512, e_lds, stream>>>(TAB, PB1, PB2, b0W1, HM, addInfo,
                                           nbrIdx, offs, SORTED, b0b2, POOLED);
  resout_kernel<1><<<NTILE / 4, 256, 0, stream>>>(
      POOLED, PWo, b0bo, interp, RES, TAB, PW1m + 20480, b1b1, HM,
      nullptr, nullptr, nullptr, nullptr, nullptr);

  // ---- block 1 ----
  edge_kernel<<<256, 512, e_lds, stream>>>(TAB, PB1 + 20480, PB2 + 16384, b1W1,
                                           HM, addInfo, nbrIdx, offs, SORTED,
                                           b1b2, POOLED);
  resout_kernel<0><<<NTILE / 4, 256, 0, stream>>>(
      POOLED, PWo + 18432, b1bo, RES, nullptr, nullptr, nullptr, nullptr,
      nullptr, PfW1, fb1, fW2, fb2, (float*)d_out);
}

// Round 11
// 236.723 us; speedup vs baseline: 1.0390x; 1.0390x over previous
//
#include <hip/hip_runtime.h>

#define NSEG 15872
#define DD 129
#define HH 128
#define NTILE (NSEG / 16)  // 992 node tiles

typedef __attribute__((ext_vector_type(8))) short s16x8;
typedef __attribute__((ext_vector_type(4))) float f32x4;

__device__ __forceinline__ unsigned short f2bf(float x) {
  union { float f; unsigned u; } c; c.f = x;
  unsigned r = c.u + 0x7FFFu + ((c.u >> 16) & 1u);
  return (unsigned short)(r >> 16);
}

// ---------------------------------------------------------------------------
// Generic MFMA B-fragment packer: out[(g*N + n)*8 + i] =
//   bf16(W[(rowBase + g*8+i)*ld + n])  (0 outside kLimit/ncols)
// ---------------------------------------------------------------------------
__device__ __forceinline__ void packB(short* out, int idx, const float* W,
                                      int N, int ld, int ncols, int kLimit,
                                      int rowBase) {
  const int i = idx & 7;
  const int n = (idx >> 3) % N;
  const int g = idx / (8 * N);
  const int row = g * 8 + i;
  float v = 0.f;
  if (row < kLimit && n < ncols) v = W[(long)(rowBase + row) * ld + n];
  out[idx] = (short)f2bf(v);
}

// W2 packer with K-permutation: packed K-position k' holds original W2 row
// k = (k'&7)*16 + (k'>>3), matching the bounce layout (k' = n16*8+nf).
__device__ __forceinline__ void packB2perm(short* out, int idx, const float* W) {
  const int i = idx & 7;
  const int n = (idx >> 3) & 127;
  const int g = idx >> 10;
  const int kp = g * 8 + i;
  const int k = ((kp & 7) << 4) + (kp >> 3);
  out[idx] = (short)f2bf(W[(long)k * HH + n]);
}

// ---------------------------------------------------------------------------
// prep_all: block 0 = scan + counting-sort-by-size, both with PARALLEL
// Hillis-Steele scans (R10's serial t==0 loops cost 60 us on one thread);
// blocks 1..632 = weight packing; rest = bf16 TAB.
// ---------------------------------------------------------------------------
#define PACK_IDS 161792  // 40960+32768+36864+40960+10240
#define TAB_IDS (NSEG * 160)
__global__ __launch_bounds__(256) void prep_all_kernel(
    const int* __restrict__ sizes, int* __restrict__ offs,
    int* __restrict__ sorted,
    const float* __restrict__ interp, unsigned short* __restrict__ tab,
    const float* __restrict__ W1b0, const float* __restrict__ W1b1,
    const float* __restrict__ W2b0, const float* __restrict__ W2b1,
    const float* __restrict__ Wob0, const float* __restrict__ Wob1,
    const float* __restrict__ fW1, short* __restrict__ PB1,
    short* __restrict__ PB2, short* __restrict__ PWo,
    short* __restrict__ PW1m, short* __restrict__ PfW1) {
  if (blockIdx.x == 0) {
    __shared__ int sums[256];
    __shared__ int tsum[256];
    __shared__ int bins[1024];
    const int t = threadIdx.x;
    const int chunk = (NSEG + 255) >> 8;
    const int s0 = t * chunk, s1 = min(s0 + chunk, NSEG);
    int s = 0;
    for (int i = s0; i < s1; ++i) s += sizes[i];
    sums[t] = s;
    __syncthreads();
    // parallel inclusive scan over 256 chunk-sums (8 steps)
    for (int d = 1; d < 256; d <<= 1) {
      int u = (t >= d) ? sums[t - d] : 0;
      __syncthreads();
      sums[t] += u;
      __syncthreads();
    }
    int a = sums[t] - s;  // exclusive prefix of this chunk
    for (int i = s0; i < s1; ++i) { offs[i] = a; a += sizes[i]; }
    if (t == 255) offs[NSEG] = a;
    // counting sort of segment ids by size (ascending) -> sorted[]
    for (int i = t; i < 1024; i += 256) bins[i] = 0;
    __syncthreads();
    for (int i = t; i < NSEG; i += 256) {
      int sz = sizes[i]; sz = sz < 0 ? 0 : (sz > 1023 ? 1023 : sz);
      atomicAdd(&bins[sz], 1);
    }
    __syncthreads();
    // parallel exclusive scan of 1024 bins: 4 bins/thread + 8-step scan
    const int c0 = bins[t * 4], c1 = bins[t * 4 + 1];
    const int c2 = bins[t * 4 + 2], c3 = bins[t * 4 + 3];
    const int loc = c0 + c1 + c2 + c3;
    tsum[t] = loc;
    __syncthreads();
    for (int d = 1; d < 256; d <<= 1) {
      int u = (t >= d) ? tsum[t - d] : 0;
      __syncthreads();
      tsum[t] += u;
      __syncthreads();
    }
    const int base = tsum[t] - loc;
    bins[t * 4]     = base;
    bins[t * 4 + 1] = base + c0;
    bins[t * 4 + 2] = base + c0 + c1;
    bins[t * 4 + 3] = base + c0 + c1 + c2;
    __syncthreads();
    for (int i = t; i < NSEG; i += 256) {
      int sz = sizes[i]; sz = sz < 0 ? 0 : (sz > 1023 ? 1023 : sz);
      int pos = atomicAdd(&bins[sz], 1);
      sorted[pos] = i;
    }
    return;
  }
  int id = (blockIdx.x - 1) * 256 + threadIdx.x;
  if (id < PACK_IDS) {
    if (id < 40960) {  // W1 neighbor half, K 129->160, N 128
      packB(PB1 + (id / 20480) * 20480, id % 20480, (id < 20480) ? W1b0 : W1b1,
            128, 128, 128, 129, 0);
      return;
    }
    id -= 40960;
    if (id < 32768) {  // W2 (K-permuted), K 128, N 128
      packB2perm(PB2 + (id / 16384) * 16384, id % 16384,
                 (id < 16384) ? W2b0 : W2b1);
      return;
    }
    id -= 32768;
    if (id < 36864) {  // Wo, K 128, N 129->144
      packB(PWo + (id / 18432) * 18432, id % 18432, (id < 18432) ? Wob0 : Wob1,
            144, 129, 129, 128, 0);
      return;
    }
    id -= 36864;
    if (id < 40960) {  // W1 main half (rows 129..257), K 129->160, N 128
      packB(PW1m + (id / 20480) * 20480, id % 20480, (id < 20480) ? W1b0 : W1b1,
            128, 128, 128, 129, 129);
      return;
    }
    id -= 40960;
    packB(PfW1, id, fW1, 64, 64, 64, 129, 0);  // fW1 K 129->160, N 64
    return;
  }
  id -= PACK_IDS;
  if (id < TAB_IDS) {
    const int n = id / 160, k = id - n * 160;
    tab[id] = (k < DD) ? f2bf(interp[(long)n * DD + k]) : (unsigned short)0;
  }
}

// ---------------------------------------------------------------------------
// HM = b1 + tab @ W1main  (dense MFMA over 16-node tiles; block-0 only)
// ---------------------------------------------------------------------------
__global__ __launch_bounds__(256) void hmprep_kernel(
    const unsigned short* __restrict__ tab, const short* __restrict__ PW1m,
    const float* __restrict__ b1, float* __restrict__ Hm) {
  const int lane = threadIdx.x & 63, w = threadIdx.x >> 6;
  const int lk = lane >> 4, n16 = lane & 15;
  const int tile = blockIdx.x * 4 + w;
  const unsigned short* arow = tab + (long)(tile * 16 + n16) * 160;
  s16x8 A[5];
#pragma unroll
  for (int ks = 0; ks < 5; ++ks) A[ks] = *(const s16x8*)(arow + ks * 32 + lk * 8);
  f32x4 C[8];
#pragma unroll
  for (int nf = 0; nf < 8; ++nf) C[nf] = (f32x4){0.f, 0.f, 0.f, 0.f};
#pragma unroll
  for (int ks = 0; ks < 5; ++ks)
#pragma unroll
    for (int nf = 0; nf < 8; ++nf) {
      const s16x8 b = *(const s16x8*)(PW1m + (((ks * 4 + lk) * 128) + nf * 16 + n16) * 8);
      C[nf] = __builtin_amdgcn_mfma_f32_16x16x32_bf16(A[ks], b, C[nf], 0, 0, 0);
    }
#pragma unroll
  for (int nf = 0; nf < 8; ++nf) {
    const float bv = b1[nf * 16 + n16];
#pragma unroll
    for (int r = 0; r < 4; ++r)
      Hm[(long)(tile * 16 + lk * 4 + r) * HH + nf * 16 + n16] = C[nf][r] + bv;
  }
}

// row within a packed pair -> edge index (rows < sLo from Lo segment, rest
// from Hi; overflow rows clamp to Hi's last edge — benign under max)
__device__ __forceinline__ int pairEdge(int row, int oLo, int sLo, int oHi,
                                        int sHi) {
  int e = (row < sLo) ? (oLo + row) : (oHi + row - sLo);
  if (row >= sLo + sHi) e = oHi + sHi - 1;
  return e;
}

// ---------------------------------------------------------------------------
// edge_kernel: fused GEMM1 + GEMM2 + segment-max over PACKED segment pairs
// (smallest+largest -> every pair sums to ~32 edges, zero tile padding).
// Two pairs per wave in lockstep (each LDS B-frag read feeds two MFMAs).
// Bounce tile uses K-permuted layout (b128 writes); PB2 rows permuted.
// ---------------------------------------------------------------------------
__global__ __launch_bounds__(512, 2) void edge_kernel(
    const unsigned short* __restrict__ tab, const short* __restrict__ PB1,
    const short* __restrict__ PB2, const float* __restrict__ W1,
    const float* __restrict__ Hm, const float* __restrict__ iou,
    const int* __restrict__ nbrIdx, const int* __restrict__ offs,
    const int* __restrict__ sorted, const float* __restrict__ b2,
    unsigned short* __restrict__ pooled) {
  extern __shared__ __align__(16) char smem[];
  short* Bs1 = (short*)smem;                  // 40960 B
  short* Bs2 = (short*)(smem + 40960);        // 32768 B
  short* stAll = (short*)(smem + 73728);      // 8 waves * 2 * 16*136*2 B
  {
    const f32x4* s1 = (const f32x4*)PB1;
    f32x4* d1 = (f32x4*)Bs1;
    for (int i = threadIdx.x; i < 2560; i += 512) d1[i] = s1[i];
    const f32x4* s2 = (const f32x4*)PB2;
    f32x4* d2 = (f32x4*)Bs2;
    for (int i = threadIdx.x; i < 2048; i += 512) d2[i] = s2[i];
  }
  __syncthreads();

  const int lane = threadIdx.x & 63;
  const int w = threadIdx.x >> 6;
  const int lk = lane >> 4, n16 = lane & 15;
  short* stA = stAll + w * 2 * (16 * 136);
  short* stB = stA + 16 * 136;

  float wv[8], bv[8];
#pragma unroll
  for (int nf = 0; nf < 8; ++nf) {
    wv[nf] = W1[258 * HH + nf * 16 + n16];
    bv[nf] = b2[nf * 16 + n16];
  }

  const int wid = (blockIdx.x << 3) + w;
  const int nw = gridDim.x << 3;
  const int npairs = NSEG >> 1;

  for (int p = wid; p < npairs; p += 2 * nw) {
    const int pA = p;
    int pB = p + nw;
    if (pB >= npairs) pB = pA;  // duplicate slot (benign)
    const int segLoA = sorted[pA], segHiA = sorted[NSEG - 1 - pA];
    const int segLoB = sorted[pB], segHiB = sorted[NSEG - 1 - pB];
    const int oLoA = offs[segLoA], sLoA = offs[segLoA + 1] - oLoA;
    const int oHiA = offs[segHiA], sHiA = offs[segHiA + 1] - oHiA;
    const int oLoB = offs[segLoB], sLoB = offs[segLoB + 1] - oLoB;
    const int oHiB = offs[segHiB], sHiB = offs[segHiB + 1] - oHiB;
    const int nt = (max(sLoA + sHiA, sLoB + sHiB) + 15) >> 4;

    float hmLoA[8], hmHiA[8], hmLoB[8], hmHiB[8];
    float pmLoA[8], pmHiA[8], pmLoB[8], pmHiB[8];
#pragma unroll
    for (int nf = 0; nf < 8; ++nf) {
      const int col = nf * 16 + n16;
      hmLoA[nf] = Hm[(long)segLoA * HH + col];
      hmHiA[nf] = Hm[(long)segHiA * HH + col];
      hmLoB[nf] = Hm[(long)segLoB * HH + col];
      hmHiB[nf] = Hm[(long)segHiB * HH + col];
      pmLoA[nf] = 0.f; pmHiA[nf] = 0.f; pmLoB[nf] = 0.f; pmHiB[nf] = 0.f;
    }

    for (int t = 0; t < nt; ++t) {
      const int row16 = (t << 4) + n16;
      const int eA = pairEdge(row16, oLoA, sLoA, oHiA, sHiA);
      const int eB = pairEdge(row16, oLoB, sLoB, oHiB, sHiB);
      const unsigned short* rA = tab + (long)nbrIdx[eA] * 160;
      const unsigned short* rB = tab + (long)nbrIdx[eB] * 160;
      s16x8 AA[5], AB[5];
#pragma unroll
      for (int ks = 0; ks < 5; ++ks) {
        AA[ks] = *(const s16x8*)(rA + ks * 32 + lk * 8);
        AB[ks] = *(const s16x8*)(rB + ks * 32 + lk * 8);
      }
      float ioA[4], ioB[4];
#pragma unroll
      for (int r = 0; r < 4; ++r) {
        const int row = (t << 4) + lk * 4 + r;
        ioA[r] = iou[pairEdge(row, oLoA, sLoA, oHiA, sHiA)];
        ioB[r] = iou[pairEdge(row, oLoB, sLoB, oHiB, sHiB)];
      }
      // GEMM1 (B read once, two MFMAs)
      f32x4 C1A[8], C1B[8];
#pragma unroll
      for (int nf = 0; nf < 8; ++nf) {
        C1A[nf] = (f32x4){0.f, 0.f, 0.f, 0.f};
        C1B[nf] = (f32x4){0.f, 0.f, 0.f, 0.f};
      }
#pragma unroll
      for (int ks = 0; ks < 5; ++ks)
#pragma unroll
        for (int nf = 0; nf < 8; ++nf) {
          const s16x8 b = *(const s16x8*)(Bs1 + (((ks * 4 + lk) * 128) + nf * 16 + n16) * 8);
          C1A[nf] = __builtin_amdgcn_mfma_f32_16x16x32_bf16(AA[ks], b, C1A[nf], 0, 0, 0);
          C1B[nf] = __builtin_amdgcn_mfma_f32_16x16x32_bf16(AB[ks], b, C1B[nf], 0, 0, 0);
        }
      // bounce: 8 nf-values per row -> one b128 (K-permuted layout);
      // Hm selected per row by segment membership
#pragma unroll
      for (int r = 0; r < 4; ++r) {
        const int row = (t << 4) + lk * 4 + r;
        const bool lA = row < sLoA, lB = row < sLoB;
        s16x8 oA, oB;
#pragma unroll
        for (int nf = 0; nf < 8; ++nf) {
          const float hA = lA ? hmLoA[nf] : hmHiA[nf];
          const float hB = lB ? hmLoB[nf] : hmHiB[nf];
          oA[nf] = (short)f2bf(fmaxf(C1A[nf][r] + ioA[r] * wv[nf] + hA, 0.f));
          oB[nf] = (short)f2bf(fmaxf(C1B[nf][r] + ioB[r] * wv[nf] + hB, 0.f));
        }
        *(s16x8*)(stA + (lk * 4 + r) * 136 + n16 * 8) = oA;
        *(s16x8*)(stB + (lk * 4 + r) * 136 + n16 * 8) = oB;
      }
      // GEMM2 A-frags from LDS (row=n16 edge, k'=ks*32+lk*8)
      s16x8 A2A[4], A2B[4];
#pragma unroll
      for (int ks = 0; ks < 4; ++ks) {
        A2A[ks] = *(const s16x8*)(stA + n16 * 136 + ks * 32 + lk * 8);
        A2B[ks] = *(const s16x8*)(stB + n16 * 136 + ks * 32 + lk * 8);
      }
      f32x4 C2A[8], C2B[8];
#pragma unroll
      for (int nf = 0; nf < 8; ++nf) {
        C2A[nf] = (f32x4){0.f, 0.f, 0.f, 0.f};
        C2B[nf] = (f32x4){0.f, 0.f, 0.f, 0.f};
      }
#pragma unroll
      for (int ks = 0; ks < 4; ++ks)
#pragma unroll
        for (int nf = 0; nf < 8; ++nf) {
          const s16x8 b = *(const s16x8*)(Bs2 + (((ks * 4 + lk) * 128) + nf * 16 + n16) * 8);
          C2A[nf] = __builtin_amdgcn_mfma_f32_16x16x32_bf16(A2A[ks], b, C2A[nf], 0, 0, 0);
          C2B[nf] = __builtin_amdgcn_mfma_f32_16x16x32_bf16(A2B[ks], b, C2B[nf], 0, 0, 0);
        }
      // per-row segment-split max update
#pragma unroll
      for (int r = 0; r < 4; ++r) {
        const int row = (t << 4) + lk * 4 + r;
        const bool lA = row < sLoA, lB = row < sLoB;
#pragma unroll
        for (int nf = 0; nf < 8; ++nf) {
          const float vA = C2A[nf][r] + bv[nf];
          const float vB = C2B[nf][r] + bv[nf];
          if (lA) pmLoA[nf] = fmaxf(pmLoA[nf], vA);
          else    pmHiA[nf] = fmaxf(pmHiA[nf], vA);
          if (lB) pmLoB[nf] = fmaxf(pmLoB[nf], vB);
          else    pmHiB[nf] = fmaxf(pmHiB[nf], vB);
        }
      }
    }
#pragma unroll
    for (int nf = 0; nf < 8; ++nf) {
      float a = pmLoA[nf], b = pmHiA[nf], c = pmLoB[nf], d = pmHiB[nf];
      a = fmaxf(a, __shfl_xor(a, 16, 64)); a = fmaxf(a, __shfl_xor(a, 32, 64));
      b = fmaxf(b, __shfl_xor(b, 16, 64)); b = fmaxf(b, __shfl_xor(b, 32, 64));
      c = fmaxf(c, __shfl_xor(c, 16, 64)); c = fmaxf(c, __shfl_xor(c, 32, 64));
      d = fmaxf(d, __shfl_xor(d, 16, 64)); d = fmaxf(d, __shfl_xor(d, 32, 64));
      pmLoA[nf] = a; pmHiA[nf] = b; pmLoB[nf] = c; pmHiB[nf] = d;
    }
    if (lane < 16) {
#pragma unroll
      for (int nf = 0; nf < 8; ++nf) {
        const int col = nf * 16 + n16;
        pooled[(long)segLoA * HH + col] = f2bf(pmLoA[nf]);
        pooled[(long)segHiA * HH + col] = f2bf(pmHiA[nf]);
        pooled[(long)segLoB * HH + col] = f2bf(pmLoB[nf]);
        pooled[(long)segHiB * HH + col] = f2bf(pmHiB[nf]);
      }
    }
  }
}

// ---------------------------------------------------------------------------
// resout: RES = resIn + bo + pooled @ Wo (MFMA). Then, via a bf16 LDS bounce
// of the result row:
//   NEXT=1: write resOut fp32 + TAB bf16 and compute HM_next = b1n + res@W1m.
//   NEXT=0: fused final head out = relu(res@fW1+fb1)@fW2 + fb2.
// ---------------------------------------------------------------------------
template <int NEXT>
__global__ __launch_bounds__(256) void resout_kernel(
    const unsigned short* __restrict__ pooled, const short* __restrict__ PWo,
    const float* __restrict__ bo, const float* __restrict__ resIn,
    float* __restrict__ resOut, unsigned short* __restrict__ tab,
    const short* __restrict__ PW1mN, const float* __restrict__ b1n,
    float* __restrict__ HmOut,
    const short* __restrict__ PfW1, const float* __restrict__ fb1,
    const float* __restrict__ fW2, const float* __restrict__ fb2,
    float* __restrict__ outFinal) {
  __shared__ short stS[4][16 * 168];
  const int lane = threadIdx.x & 63, w = threadIdx.x >> 6;
  const int lk = lane >> 4, n16 = lane & 15;
  short* st = stS[w];

  // zero the k-pad cols 129..160 once (A-frag reads touch up to col 159)
  {
    const int row = lane >> 2, c0 = 129 + (lane & 3) * 8;
#pragma unroll
    for (int i = 0; i < 8; ++i) st[row * 168 + c0 + i] = 0;
  }

  const int tile = blockIdx.x * 4 + w;
  const unsigned short* arow = pooled + (long)(tile * 16 + n16) * HH;
  s16x8 A[4];
#pragma unroll
  for (int ks = 0; ks < 4; ++ks) A[ks] = *(const s16x8*)(arow + ks * 32 + lk * 8);
  f32x4 C[9];
#pragma unroll
  for (int nf = 0; nf < 9; ++nf) C[nf] = (f32x4){0.f, 0.f, 0.f, 0.f};
#pragma unroll
  for (int ks = 0; ks < 4; ++ks)
#pragma unroll
    for (int nf = 0; nf < 9; ++nf) {
      const s16x8 b = *(const s16x8*)(PWo + (((ks * 4 + lk) * 144) + nf * 16 + n16) * 8);
      C[nf] = __builtin_amdgcn_mfma_f32_16x16x32_bf16(A[ks], b, C[nf], 0, 0, 0);
    }

#pragma unroll
  for (int nf = 0; nf < 8; ++nf) {
    const int col = nf * 16 + n16;
    const float bov = bo[col];
#pragma unroll
    for (int r = 0; r < 4; ++r) {
      const int row = lk * 4 + r;
      const long node = tile * 16 + row;
      const float res = resIn[node * DD + col] + bov + C[nf][r];
      if (NEXT) {
        resOut[node * DD + col] = res;
        tab[node * 160 + col] = f2bf(res);
      }
      st[row * 168 + col] = (short)f2bf(res);
    }
  }
  if (n16 == 0) {
#pragma unroll
    for (int r = 0; r < 4; ++r) {
      const int row = lk * 4 + r;
      const long node = tile * 16 + row;
      const float res = resIn[node * DD + 128] + bo[128] + C[8][r];
      if (NEXT) {
        resOut[node * DD + 128] = res;
        tab[node * 160 + 128] = f2bf(res);
      }
      st[row * 168 + 128] = (short)f2bf(res);
    }
  }

  // A-frags of res from the bounce tile (row=n16 node, k=ks*32+lk*8, pad 0)
  s16x8 A5[5];
#pragma unroll
  for (int ks = 0; ks < 5; ++ks)
    A5[ks] = *(const s16x8*)(st + n16 * 168 + ks * 32 + lk * 8);

  if (NEXT) {
    f32x4 H[8];
#pragma unroll
    for (int nf = 0; nf < 8; ++nf) H[nf] = (f32x4){0.f, 0.f, 0.f, 0.f};
#pragma unroll
    for (int ks = 0; ks < 5; ++ks)
#pragma unroll
      for (int nf = 0; nf < 8; ++nf) {
        const s16x8 b = *(const s16x8*)(PW1mN + (((ks * 4 + lk) * 128) + nf * 16 + n16) * 8);
        H[nf] = __builtin_amdgcn_mfma_f32_16x16x32_bf16(A5[ks], b, H[nf], 0, 0, 0);
      }
#pragma unroll
    for (int nf = 0; nf < 8; ++nf) {
      const float bv = b1n[nf * 16 + n16];
#pragma unroll
      for (int r = 0; r < 4; ++r)
        HmOut[(long)(tile * 16 + lk * 4 + r) * HH + nf * 16 + n16] = H[nf][r] + bv;
    }
  } else {
    f32x4 Ch[4];
#pragma unroll
    for (int nf = 0; nf < 4; ++nf) Ch[nf] = (f32x4){0.f, 0.f, 0.f, 0.f};
#pragma unroll
    for (int ks = 0; ks < 5; ++ks)
#pragma unroll
      for (int nf = 0; nf < 4; ++nf) {
        const s16x8 b = *(const s16x8*)(PfW1 + (((ks * 4 + lk) * 64) + nf * 16 + n16) * 8);
        Ch[nf] = __builtin_amdgcn_mfma_f32_16x16x32_bf16(A5[ks], b, Ch[nf], 0, 0, 0);
      }
    float b1v[4], w2v[4];
#pragma unroll
    for (int nf = 0; nf < 4; ++nf) {
      b1v[nf] = fb1[nf * 16 + n16];
      w2v[nf] = fW2[nf * 16 + n16];
    }
#pragma unroll
    for (int r = 0; r < 4; ++r) {
      float s = 0.f;
#pragma unroll
      for (int nf = 0; nf < 4; ++nf)
        s += fmaxf(Ch[nf][r] + b1v[nf], 0.f) * w2v[nf];
      s += __shfl_xor(s, 1, 64);
      s += __shfl_xor(s, 2, 64);
      s += __shfl_xor(s, 4, 64);
      s += __shfl_xor(s, 8, 64);
      if (n16 == 0) outFinal[tile * 16 + lk * 4 + r] = s + fb2[0];
    }
  }
}

// ---------------------------------------------------------------------------
extern "C" void kernel_launch(void* const* d_in, const int* in_sizes, int n_in,
                              void* d_out, int out_size, void* d_ws, size_t ws_size,
                              hipStream_t stream) {
  const float* interp  = (const float*)d_in[0];
  const float* addInfo = (const float*)d_in[1];
  const int* sizes     = (const int*)d_in[2];
  const int* nbrIdx    = (const int*)d_in[3];
  const float* b0W1 = (const float*)d_in[5];
  const float* b0b1 = (const float*)d_in[6];
  const float* b0W2 = (const float*)d_in[7];
  const float* b0b2 = (const float*)d_in[8];
  const float* b0Wo = (const float*)d_in[9];
  const float* b0bo = (const float*)d_in[10];
  const float* b1W1 = (const float*)d_in[11];
  const float* b1b1 = (const float*)d_in[12];
  const float* b1W2 = (const float*)d_in[13];
  const float* b1b2 = (const float*)d_in[14];
  const float* b1Wo = (const float*)d_in[15];
  const float* b1bo = (const float*)d_in[16];
  const float* fW1  = (const float*)d_in[17];
  const float* fb1  = (const float*)d_in[18];
  const float* fW2  = (const float*)d_in[19];
  const float* fb2  = (const float*)d_in[20];

  char* ws = (char*)d_ws;
  int*            offs  = (int*)(ws + 0);                    // 65536
  short*          PB1   = (short*)(ws + 65536);              // 81920
  short*          PB2   = (short*)(ws + 147456);             // 65536
  short*          PWo   = (short*)(ws + 212992);             // 73728
  short*          PW1m  = (short*)(ws + 286720);             // 81920
  short*          PfW1  = (short*)(ws + 368640);             // 20480 -> pad
  unsigned short* TAB   = (unsigned short*)(ws + 393216);    // N*160*2
  float*          HM    = (float*)(ws + 5472256);            // N*128*4
  unsigned short* POOLED= (unsigned short*)(ws + 13598720);  // N*128*2
  float*          RES   = (float*)(ws + 17661952);           // N*129*4
  int*            SORTED= (int*)(ws + 25851904);             // N*4

  const int prep_blocks = 1 + (PACK_IDS / 256) + (TAB_IDS / 256);  // 10553
  prep_all_kernel<<<prep_blocks, 256, 0, stream>>>(
      sizes, offs, SORTED, interp, TAB, b0W1, b1W1, b0W2, b1W2, b0Wo, b1Wo,
      fW1, PB1, PB2, PWo, PW1m, PfW1);

  const size_t e_lds = 40960 + 32768 + 8 * 2 * 16 * 136 * 2;  // 143360

  // ---- block 0 ----
  hmprep_kernel<<<NTILE / 4, 256, 0, stream>>>(TAB, PW1m, b0b1, HM);
  edge_kernel<<<256, 512, e_lds, stream>>>(TAB, PB1, PB2, b0W1, HM, addInfo,
                                           nbrIdx, offs, SORTED, b0b2, POOLED);
  resout_kernel<1><<<NTILE / 4, 256, 0, stream>>>(
      POOLED, PWo, b0bo, interp, RES, TAB, PW1m + 20480, b1b1, HM,
      nullptr, nullptr, nullptr, nullptr, nullptr);

  // ---- block 1 ----
  edge_kernel<<<256, 512, e_lds, stream>>>(TAB, PB1 + 20480, PB2 + 16384, b1W1,
                                           HM, addInfo, nbrIdx, offs, SORTED,
                                           b1b2, POOLED);
  resout_kernel<0><<<NTILE / 4, 256, 0, stream>>>(
      POOLED, PWo + 18432, b1bo, RES, nullptr, nullptr, nullptr, nullptr,
      nullptr, PfW1, fb1, fW2, fb2, (float*)d_out);
}

// Round 12
// 212.830 us; speedup vs baseline: 1.1556x; 1.1123x over previous
//
#include <hip/hip_runtime.h>

#define NSEG 15872
#define DD 129
#define HH 128
#define NTILE (NSEG / 16)  // 992 node tiles

typedef __attribute__((ext_vector_type(8))) short s16x8;
typedef __attribute__((ext_vector_type(4))) float f32x4;

__device__ __forceinline__ unsigned short f2bf(float x) {
  union { float f; unsigned u; } c; c.f = x;
  unsigned r = c.u + 0x7FFFu + ((c.u >> 16) & 1u);
  return (unsigned short)(r >> 16);
}

// ---------------------------------------------------------------------------
// scan_sort_kernel: single block, everything staged in LDS (R11's prep tail
// was this work with uncoalesced global loops on one CU: ~50 us).
// offs[N+1] = exclusive scan of sizes; sorted[] = segment ids by ascending
// size (counting sort; LDS scatter + coalesced dump).
// ---------------------------------------------------------------------------
__global__ __launch_bounds__(256) void scan_sort_kernel(
    const int* __restrict__ sizes, int* __restrict__ offs,
    int* __restrict__ sorted) {
  extern __shared__ int dynS[];      // 2 * NSEG ints
  int* szS = dynS;
  int* tmpS = dynS + NSEG;
  __shared__ int sums[256];
  __shared__ int bins[1024];
  const int t = threadIdx.x;

  for (int i = t; i < NSEG; i += 256) szS[i] = sizes[i];  // coalesced
  for (int i = t; i < 1024; i += 256) bins[i] = 0;
  __syncthreads();

  // per-thread chunk sums over LDS (chunk=62; lane stride 62 words -> 2-way
  // bank aliasing = free)
  const int chunk = (NSEG + 255) >> 8;
  const int s0 = t * chunk, s1 = min(s0 + chunk, NSEG);
  int s = 0;
  for (int i = s0; i < s1; ++i) s += szS[i];
  sums[t] = s;
  __syncthreads();
  for (int d = 1; d < 256; d <<= 1) {
    int u = (t >= d) ? sums[t - d] : 0;
    __syncthreads();
    sums[t] += u;
    __syncthreads();
  }
  int a = sums[t] - s;  // exclusive prefix of this chunk
  for (int i = s0; i < s1; ++i) { tmpS[i] = a; a += szS[i]; }
  __syncthreads();
  for (int i = t; i < NSEG; i += 256) offs[i] = tmpS[i];  // coalesced
  if (t == 255) offs[NSEG] = a;

  // histogram (coalesced LDS reads, LDS atomics)
  for (int i = t; i < NSEG; i += 256) {
    int sz = szS[i]; sz = sz < 0 ? 0 : (sz > 1023 ? 1023 : sz);
    atomicAdd(&bins[sz], 1);
  }
  __syncthreads();
  // parallel exclusive scan of 1024 bins (4/thread + 8-step scan)
  const int c0 = bins[t * 4], c1 = bins[t * 4 + 1];
  const int c2 = bins[t * 4 + 2], c3 = bins[t * 4 + 3];
  const int loc = c0 + c1 + c2 + c3;
  sums[t] = loc;
  __syncthreads();
  for (int d = 1; d < 256; d <<= 1) {
    int u = (t >= d) ? sums[t - d] : 0;
    __syncthreads();
    sums[t] += u;
    __syncthreads();
  }
  const int base = sums[t] - loc;
  bins[t * 4]     = base;
  bins[t * 4 + 1] = base + c0;
  bins[t * 4 + 2] = base + c0 + c1;
  bins[t * 4 + 3] = base + c0 + c1 + c2;
  __syncthreads();
  // scatter into LDS, then coalesced dump
  for (int i = t; i < NSEG; i += 256) {
    int sz = szS[i]; sz = sz < 0 ? 0 : (sz > 1023 ? 1023 : sz);
    int pos = atomicAdd(&bins[sz], 1);
    tmpS[pos] = i;
  }
  __syncthreads();
  for (int i = t; i < NSEG; i += 256) sorted[i] = tmpS[i];  // coalesced
}

// ---------------------------------------------------------------------------
// Vectorized (x8) MFMA B-fragment packers: one s16x8 store per thread.
// ---------------------------------------------------------------------------
__device__ __forceinline__ void packB8(short* out, int idx8, const float* W,
                                       int N, int ld, int ncols, int kLimit,
                                       int rowBase) {
  const int n = (idx8 >> 3) % N;
  const int g = idx8 / (8 * N);
  s16x8 o;
#pragma unroll
  for (int i = 0; i < 8; ++i) {
    const int row = g * 8 + i;
    float v = 0.f;
    if (row < kLimit && n < ncols) v = W[(long)(rowBase + row) * ld + n];
    o[i] = (short)f2bf(v);
  }
  *(s16x8*)(out + idx8) = o;
}

// W2 with K-permutation: for aligned idx8, packed rows i*16+g (bounce layout
// k' = n16*8+nf; PB2 rows permuted to match).
__device__ __forceinline__ void packB2perm8(short* out, int idx8,
                                            const float* W) {
  const int n = (idx8 >> 3) & 127;
  const int g = idx8 >> 10;
  s16x8 o;
#pragma unroll
  for (int i = 0; i < 8; ++i)
    o[i] = (short)f2bf(W[(long)(i * 16 + g) * HH + n]);
  *(s16x8*)(out + idx8) = o;
}

// ---------------------------------------------------------------------------
// pack_tab_kernel: weight packing + bf16 node table, 8 elements per thread.
// ---------------------------------------------------------------------------
#define PACK_IDS 161792  // 40960+32768+36864+40960+10240
#define TAB_IDS (NSEG * 160)
#define PACKV (PACK_IDS / 8)  // 20224
#define TABV (TAB_IDS / 8)    // 317440
__global__ __launch_bounds__(256) void pack_tab_kernel(
    const float* __restrict__ interp, unsigned short* __restrict__ tab,
    const float* __restrict__ W1b0, const float* __restrict__ W1b1,
    const float* __restrict__ W2b0, const float* __restrict__ W2b1,
    const float* __restrict__ Wob0, const float* __restrict__ Wob1,
    const float* __restrict__ fW1, short* __restrict__ PB1,
    short* __restrict__ PB2, short* __restrict__ PWo,
    short* __restrict__ PW1m, short* __restrict__ PfW1) {
  int vid = blockIdx.x * 256 + threadIdx.x;
  if (vid < PACKV) {
    int idx = vid * 8;
    if (idx < 40960) {  // W1 neighbor half, K 129->160, N 128
      packB8(PB1 + (idx / 20480) * 20480, idx % 20480,
             (idx < 20480) ? W1b0 : W1b1, 128, 128, 128, 129, 0);
      return;
    }
    idx -= 40960;
    if (idx < 32768) {  // W2 (K-permuted), K 128, N 128
      packB2perm8(PB2 + (idx / 16384) * 16384, idx % 16384,
                  (idx < 16384) ? W2b0 : W2b1);
      return;
    }
    idx -= 32768;
    if (idx < 36864) {  // Wo, K 128, N 129->144
      packB8(PWo + (idx / 18432) * 18432, idx % 18432,
             (idx < 18432) ? Wob0 : Wob1, 144, 129, 129, 128, 0);
      return;
    }
    idx -= 36864;
    if (idx < 40960) {  // W1 main half (rows 129..257), K 129->160, N 128
      packB8(PW1m + (idx / 20480) * 20480, idx % 20480,
             (idx < 20480) ? W1b0 : W1b1, 128, 128, 128, 129, 129);
      return;
    }
    idx -= 40960;
    packB8(PfW1, idx, fW1, 64, 64, 64, 129, 0);  // fW1 K 129->160, N 64
    return;
  }
  vid -= PACKV;
  if (vid < TABV) {
    const int n = vid / 20;
    const int g = vid - n * 20;
    s16x8 o = (s16x8){0, 0, 0, 0, 0, 0, 0, 0};
    if (g < 16) {
      const float* src = interp + (long)n * DD + g * 8;
#pragma unroll
      for (int i = 0; i < 8; ++i) o[i] = (short)f2bf(src[i]);
    } else if (g == 16) {
      o[0] = (short)f2bf(interp[(long)n * DD + 128]);
    }
    *(s16x8*)(tab + (long)vid * 8) = o;
  }
}

// ---------------------------------------------------------------------------
// HM = b1 + tab @ W1main  (dense MFMA over 16-node tiles; block-0 only)
// ---------------------------------------------------------------------------
__global__ __launch_bounds__(256) void hmprep_kernel(
    const unsigned short* __restrict__ tab, const short* __restrict__ PW1m,
    const float* __restrict__ b1, float* __restrict__ Hm) {
  const int lane = threadIdx.x & 63, w = threadIdx.x >> 6;
  const int lk = lane >> 4, n16 = lane & 15;
  const int tile = blockIdx.x * 4 + w;
  const unsigned short* arow = tab + (long)(tile * 16 + n16) * 160;
  s16x8 A[5];
#pragma unroll
  for (int ks = 0; ks < 5; ++ks) A[ks] = *(const s16x8*)(arow + ks * 32 + lk * 8);
  f32x4 C[8];
#pragma unroll
  for (int nf = 0; nf < 8; ++nf) C[nf] = (f32x4){0.f, 0.f, 0.f, 0.f};
#pragma unroll
  for (int ks = 0; ks < 5; ++ks)
#pragma unroll
    for (int nf = 0; nf < 8; ++nf) {
      const s16x8 b = *(const s16x8*)(PW1m + (((ks * 4 + lk) * 128) + nf * 16 + n16) * 8);
      C[nf] = __builtin_amdgcn_mfma_f32_16x16x32_bf16(A[ks], b, C[nf], 0, 0, 0);
    }
#pragma unroll
  for (int nf = 0; nf < 8; ++nf) {
    const float bv = b1[nf * 16 + n16];
#pragma unroll
    for (int r = 0; r < 4; ++r)
      Hm[(long)(tile * 16 + lk * 4 + r) * HH + nf * 16 + n16] = C[nf][r] + bv;
  }
}

// row within a packed pair -> edge index (rows < sLo from Lo segment, rest
// from Hi; overflow rows clamp to Hi's last edge — benign under max)
__device__ __forceinline__ int pairEdge(int row, int oLo, int sLo, int oHi,
                                        int sHi) {
  int e = (row < sLo) ? (oLo + row) : (oHi + row - sLo);
  if (row >= sLo + sHi) e = oHi + sHi - 1;
  return e;
}

// ---------------------------------------------------------------------------
// edge_kernel: fused GEMM1 + GEMM2 + segment-max over PACKED segment pairs
// (smallest+largest -> every pair sums to ~32 edges, zero tile padding).
// Two pairs per wave in lockstep (each LDS B-frag read feeds two MFMAs).
// Bounce tile uses K-permuted layout (b128 writes); PB2 rows permuted.
// ---------------------------------------------------------------------------
__global__ __launch_bounds__(512, 2) void edge_kernel(
    const unsigned short* __restrict__ tab, const short* __restrict__ PB1,
    const short* __restrict__ PB2, const float* __restrict__ W1,
    const float* __restrict__ Hm, const float* __restrict__ iou,
    const int* __restrict__ nbrIdx, const int* __restrict__ offs,
    const int* __restrict__ sorted, const float* __restrict__ b2,
    unsigned short* __restrict__ pooled) {
  extern __shared__ __align__(16) char smem[];
  short* Bs1 = (short*)smem;                  // 40960 B
  short* Bs2 = (short*)(smem + 40960);        // 32768 B
  short* stAll = (short*)(smem + 73728);      // 8 waves * 2 * 16*136*2 B
  {
    const f32x4* s1 = (const f32x4*)PB1;
    f32x4* d1 = (f32x4*)Bs1;
    for (int i = threadIdx.x; i < 2560; i += 512) d1[i] = s1[i];
    const f32x4* s2 = (const f32x4*)PB2;
    f32x4* d2 = (f32x4*)Bs2;
    for (int i = threadIdx.x; i < 2048; i += 512) d2[i] = s2[i];
  }
  __syncthreads();

  const int lane = threadIdx.x & 63;
  const int w = threadIdx.x >> 6;
  const int lk = lane >> 4, n16 = lane & 15;
  short* stA = stAll + w * 2 * (16 * 136);
  short* stB = stA + 16 * 136;

  float wv[8], bv[8];
#pragma unroll
  for (int nf = 0; nf < 8; ++nf) {
    wv[nf] = W1[258 * HH + nf * 16 + n16];
    bv[nf] = b2[nf * 16 + n16];
  }

  const int wid = (blockIdx.x << 3) + w;
  const int nw = gridDim.x << 3;
  const int npairs = NSEG >> 1;

  for (int p = wid; p < npairs; p += 2 * nw) {
    const int pA = p;
    int pB = p + nw;
    if (pB >= npairs) pB = pA;  // duplicate slot (benign)
    const int segLoA = sorted[pA], segHiA = sorted[NSEG - 1 - pA];
    const int segLoB = sorted[pB], segHiB = sorted[NSEG - 1 - pB];
    const int oLoA = offs[segLoA], sLoA = offs[segLoA + 1] - oLoA;
    const int oHiA = offs[segHiA], sHiA = offs[segHiA + 1] - oHiA;
    const int oLoB = offs[segLoB], sLoB = offs[segLoB + 1] - oLoB;
    const int oHiB = offs[segHiB], sHiB = offs[segHiB + 1] - oHiB;
    const int nt = (max(sLoA + sHiA, sLoB + sHiB) + 15) >> 4;

    float hmLoA[8], hmHiA[8], hmLoB[8], hmHiB[8];
    float pmLoA[8], pmHiA[8], pmLoB[8], pmHiB[8];
#pragma unroll
    for (int nf = 0; nf < 8; ++nf) {
      const int col = nf * 16 + n16;
      hmLoA[nf] = Hm[(long)segLoA * HH + col];
      hmHiA[nf] = Hm[(long)segHiA * HH + col];
      hmLoB[nf] = Hm[(long)segLoB * HH + col];
      hmHiB[nf] = Hm[(long)segHiB * HH + col];
      pmLoA[nf] = 0.f; pmHiA[nf] = 0.f; pmLoB[nf] = 0.f; pmHiB[nf] = 0.f;
    }

    for (int t = 0; t < nt; ++t) {
      const int row16 = (t << 4) + n16;
      const int eA = pairEdge(row16, oLoA, sLoA, oHiA, sHiA);
      const int eB = pairEdge(row16, oLoB, sLoB, oHiB, sHiB);
      const unsigned short* rA = tab + (long)nbrIdx[eA] * 160;
      const unsigned short* rB = tab + (long)nbrIdx[eB] * 160;
      s16x8 AA[5], AB[5];
#pragma unroll
      for (int ks = 0; ks < 5; ++ks) {
        AA[ks] = *(const s16x8*)(rA + ks * 32 + lk * 8);
        AB[ks] = *(const s16x8*)(rB + ks * 32 + lk * 8);
      }
      float ioA[4], ioB[4];
#pragma unroll
      for (int r = 0; r < 4; ++r) {
        const int row = (t << 4) + lk * 4 + r;
        ioA[r] = iou[pairEdge(row, oLoA, sLoA, oHiA, sHiA)];
        ioB[r] = iou[pairEdge(row, oLoB, sLoB, oHiB, sHiB)];
      }
      // GEMM1 (B read once, two MFMAs)
      f32x4 C1A[8], C1B[8];
#pragma unroll
      for (int nf = 0; nf < 8; ++nf) {
        C1A[nf] = (f32x4){0.f, 0.f, 0.f, 0.f};
        C1B[nf] = (f32x4){0.f, 0.f, 0.f, 0.f};
      }
#pragma unroll
      for (int ks = 0; ks < 5; ++ks)
#pragma unroll
        for (int nf = 0; nf < 8; ++nf) {
          const s16x8 b = *(const s16x8*)(Bs1 + (((ks * 4 + lk) * 128) + nf * 16 + n16) * 8);
          C1A[nf] = __builtin_amdgcn_mfma_f32_16x16x32_bf16(AA[ks], b, C1A[nf], 0, 0, 0);
          C1B[nf] = __builtin_amdgcn_mfma_f32_16x16x32_bf16(AB[ks], b, C1B[nf], 0, 0, 0);
        }
      // bounce: 8 nf-values per row -> one b128 (K-permuted layout);
      // Hm selected per row by segment membership
#pragma unroll
      for (int r = 0; r < 4; ++r) {
        const int row = (t << 4) + lk * 4 + r;
        const bool lA = row < sLoA, lB = row < sLoB;
        s16x8 oA, oB;
#pragma unroll
        for (int nf = 0; nf < 8; ++nf) {
          const float hA = lA ? hmLoA[nf] : hmHiA[nf];
          const float hB = lB ? hmLoB[nf] : hmHiB[nf];
          oA[nf] = (short)f2bf(fmaxf(C1A[nf][r] + ioA[r] * wv[nf] + hA, 0.f));
          oB[nf] = (short)f2bf(fmaxf(C1B[nf][r] + ioB[r] * wv[nf] + hB, 0.f));
        }
        *(s16x8*)(stA + (lk * 4 + r) * 136 + n16 * 8) = oA;
        *(s16x8*)(stB + (lk * 4 + r) * 136 + n16 * 8) = oB;
      }
      // GEMM2 A-frags from LDS (row=n16 edge, k'=ks*32+lk*8)
      s16x8 A2A[4], A2B[4];
#pragma unroll
      for (int ks = 0; ks < 4; ++ks) {
        A2A[ks] = *(const s16x8*)(stA + n16 * 136 + ks * 32 + lk * 8);
        A2B[ks] = *(const s16x8*)(stB + n16 * 136 + ks * 32 + lk * 8);
      }
      f32x4 C2A[8], C2B[8];
#pragma unroll
      for (int nf = 0; nf < 8; ++nf) {
        C2A[nf] = (f32x4){0.f, 0.f, 0.f, 0.f};
        C2B[nf] = (f32x4){0.f, 0.f, 0.f, 0.f};
      }
#pragma unroll
      for (int ks = 0; ks < 4; ++ks)
#pragma unroll
        for (int nf = 0; nf < 8; ++nf) {
          const s16x8 b = *(const s16x8*)(Bs2 + (((ks * 4 + lk) * 128) + nf * 16 + n16) * 8);
          C2A[nf] = __builtin_amdgcn_mfma_f32_16x16x32_bf16(A2A[ks], b, C2A[nf], 0, 0, 0);
          C2B[nf] = __builtin_amdgcn_mfma_f32_16x16x32_bf16(A2B[ks], b, C2B[nf], 0, 0, 0);
        }
      // per-row segment-split max update
#pragma unroll
      for (int r = 0; r < 4; ++r) {
        const int row = (t << 4) + lk * 4 + r;
        const bool lA = row < sLoA, lB = row < sLoB;
#pragma unroll
        for (int nf = 0; nf < 8; ++nf) {
          const float vA = C2A[nf][r] + bv[nf];
          const float vB = C2B[nf][r] + bv[nf];
          if (lA) pmLoA[nf] = fmaxf(pmLoA[nf], vA);
          else    pmHiA[nf] = fmaxf(pmHiA[nf], vA);
          if (lB) pmLoB[nf] = fmaxf(pmLoB[nf], vB);
          else    pmHiB[nf] = fmaxf(pmHiB[nf], vB);
        }
      }
    }
#pragma unroll
    for (int nf = 0; nf < 8; ++nf) {
      float a = pmLoA[nf], b = pmHiA[nf], c = pmLoB[nf], d = pmHiB[nf];
      a = fmaxf(a, __shfl_xor(a, 16, 64)); a = fmaxf(a, __shfl_xor(a, 32, 64));
      b = fmaxf(b, __shfl_xor(b, 16, 64)); b = fmaxf(b, __shfl_xor(b, 32, 64));
      c = fmaxf(c, __shfl_xor(c, 16, 64)); c = fmaxf(c, __shfl_xor(c, 32, 64));
      d = fmaxf(d, __shfl_xor(d, 16, 64)); d = fmaxf(d, __shfl_xor(d, 32, 64));
      pmLoA[nf] = a; pmHiA[nf] = b; pmLoB[nf] = c; pmHiB[nf] = d;
    }
    if (lane < 16) {
#pragma unroll
      for (int nf = 0; nf < 8; ++nf) {
        const int col = nf * 16 + n16;
        pooled[(long)segLoA * HH + col] = f2bf(pmLoA[nf]);
        pooled[(long)segHiA * HH + col] = f2bf(pmHiA[nf]);
        pooled[(long)segLoB * HH + col] = f2bf(pmLoB[nf]);
        pooled[(long)segHiB * HH + col] = f2bf(pmHiB[nf]);
      }
    }
  }
}

// ---------------------------------------------------------------------------
// resout: RES = resIn + bo + pooled @ Wo (MFMA). Then, via a bf16 LDS bounce
// of the result row:
//   NEXT=1: write resOut fp32 + TAB bf16 and compute HM_next = b1n + res@W1m.
//   NEXT=0: fused final head out = relu(res@fW1+fb1)@fW2 + fb2.
// ---------------------------------------------------------------------------
template <int NEXT>
__global__ __launch_bounds__(256) void resout_kernel(
    const unsigned short* __restrict__ pooled, const short* __restrict__ PWo,
    const float* __restrict__ bo, const float* __restrict__ resIn,
    float* __restrict__ resOut, unsigned short* __restrict__ tab,
    const short* __restrict__ PW1mN, const float* __restrict__ b1n,
    float* __restrict__ HmOut,
    const short* __restrict__ PfW1, const float* __restrict__ fb1,
    const float* __restrict__ fW2, const float* __restrict__ fb2,
    float* __restrict__ outFinal) {
  __shared__ short stS[4][16 * 168];
  const int lane = threadIdx.x & 63, w = threadIdx.x >> 6;
  const int lk = lane >> 4, n16 = lane & 15;
  short* st = stS[w];

  // zero the k-pad cols 129..160 once (A-frag reads touch up to col 159)
  {
    const int row = lane >> 2, c0 = 129 + (lane & 3) * 8;
#pragma unroll
    for (int i = 0; i < 8; ++i) st[row * 168 + c0 + i] = 0;
  }

  const int tile = blockIdx.x * 4 + w;
  const unsigned short* arow = pooled + (long)(tile * 16 + n16) * HH;
  s16x8 A[4];
#pragma unroll
  for (int ks = 0; ks < 4; ++ks) A[ks] = *(const s16x8*)(arow + ks * 32 + lk * 8);
  f32x4 C[9];
#pragma unroll
  for (int nf = 0; nf < 9; ++nf) C[nf] = (f32x4){0.f, 0.f, 0.f, 0.f};
#pragma unroll
  for (int ks = 0; ks < 4; ++ks)
#pragma unroll
    for (int nf = 0; nf < 9; ++nf) {
      const s16x8 b = *(const s16x8*)(PWo + (((ks * 4 + lk) * 144) + nf * 16 + n16) * 8);
      C[nf] = __builtin_amdgcn_mfma_f32_16x16x32_bf16(A[ks], b, C[nf], 0, 0, 0);
    }

#pragma unroll
  for (int nf = 0; nf < 8; ++nf) {
    const int col = nf * 16 + n16;
    const float bov = bo[col];
#pragma unroll
    for (int r = 0; r < 4; ++r) {
      const int row = lk * 4 + r;
      const long node = tile * 16 + row;
      const float res = resIn[node * DD + col] + bov + C[nf][r];
      if (NEXT) {
        resOut[node * DD + col] = res;
        tab[node * 160 + col] = f2bf(res);
      }
      st[row * 168 + col] = (short)f2bf(res);
    }
  }
  if (n16 == 0) {
#pragma unroll
    for (int r = 0; r < 4; ++r) {
      const int row = lk * 4 + r;
      const long node = tile * 16 + row;
      const float res = resIn[node * DD + 128] + bo[128] + C[8][r];
      if (NEXT) {
        resOut[node * DD + 128] = res;
        tab[node * 160 + 128] = f2bf(res);
      }
      st[row * 168 + 128] = (short)f2bf(res);
    }
  }

  // A-frags of res from the bounce tile (row=n16 node, k=ks*32+lk*8, pad 0)
  s16x8 A5[5];
#pragma unroll
  for (int ks = 0; ks < 5; ++ks)
    A5[ks] = *(const s16x8*)(st + n16 * 168 + ks * 32 + lk * 8);

  if (NEXT) {
    f32x4 H[8];
#pragma unroll
    for (int nf = 0; nf < 8; ++nf) H[nf] = (f32x4){0.f, 0.f, 0.f, 0.f};
#pragma unroll
    for (int ks = 0; ks < 5; ++ks)
#pragma unroll
      for (int nf = 0; nf < 8; ++nf) {
        const s16x8 b = *(const s16x8*)(PW1mN + (((ks * 4 + lk) * 128) + nf * 16 + n16) * 8);
        H[nf] = __builtin_amdgcn_mfma_f32_16x16x32_bf16(A5[ks], b, H[nf], 0, 0, 0);
      }
#pragma unroll
    for (int nf = 0; nf < 8; ++nf) {
      const float bv = b1n[nf * 16 + n16];
#pragma unroll
      for (int r = 0; r < 4; ++r)
        HmOut[(long)(tile * 16 + lk * 4 + r) * HH + nf * 16 + n16] = H[nf][r] + bv;
    }
  } else {
    f32x4 Ch[4];
#pragma unroll
    for (int nf = 0; nf < 4; ++nf) Ch[nf] = (f32x4){0.f, 0.f, 0.f, 0.f};
#pragma unroll
    for (int ks = 0; ks < 5; ++ks)
#pragma unroll
      for (int nf = 0; nf < 4; ++nf) {
        const s16x8 b = *(const s16x8*)(PfW1 + (((ks * 4 + lk) * 64) + nf * 16 + n16) * 8);
        Ch[nf] = __builtin_amdgcn_mfma_f32_16x16x32_bf16(A5[ks], b, Ch[nf], 0, 0, 0);
      }
    float b1v[4], w2v[4];
#pragma unroll
    for (int nf = 0; nf < 4; ++nf) {
      b1v[nf] = fb1[nf * 16 + n16];
      w2v[nf] = fW2[nf * 16 + n16];
    }
#pragma unroll
    for (int r = 0; r < 4; ++r) {
      float s = 0.f;
#pragma unroll
      for (int nf = 0; nf < 4; ++nf)
        s += fmaxf(Ch[nf][r] + b1v[nf], 0.f) * w2v[nf];
      s += __shfl_xor(s, 1, 64);
      s += __shfl_xor(s, 2, 64);
      s += __shfl_xor(s, 4, 64);
      s += __shfl_xor(s, 8, 64);
      if (n16 == 0) outFinal[tile * 16 + lk * 4 + r] = s + fb2[0];
    }
  }
}

// ---------------------------------------------------------------------------
extern "C" void kernel_launch(void* const* d_in, const int* in_sizes, int n_in,
                              void* d_out, int out_size, void* d_ws, size_t ws_size,
                              hipStream_t stream) {
  const float* interp  = (const float*)d_in[0];
  const float* addInfo = (const float*)d_in[1];
  const int* sizes     = (const int*)d_in[2];
  const int* nbrIdx    = (const int*)d_in[3];
  const float* b0W1 = (const float*)d_in[5];
  const float* b0b1 = (const float*)d_in[6];
  const float* b0W2 = (const float*)d_in[7];
  const float* b0b2 = (const float*)d_in[8];
  const float* b0Wo = (const float*)d_in[9];
  const float* b0bo = (const float*)d_in[10];
  const float* b1W1 = (const float*)d_in[11];
  const float* b1b1 = (const float*)d_in[12];
  const float* b1W2 = (const float*)d_in[13];
  const float* b1b2 = (const float*)d_in[14];
  const float* b1Wo = (const float*)d_in[15];
  const float* b1bo = (const float*)d_in[16];
  const float* fW1  = (const float*)d_in[17];
  const float* fb1  = (const float*)d_in[18];
  const float* fW2  = (const float*)d_in[19];
  const float* fb2  = (const float*)d_in[20];

  char* ws = (char*)d_ws;
  int*            offs  = (int*)(ws + 0);                    // 65536
  short*          PB1   = (short*)(ws + 65536);              // 81920
  short*          PB2   = (short*)(ws + 147456);             // 65536
  short*          PWo   = (short*)(ws + 212992);             // 73728
  short*          PW1m  = (short*)(ws + 286720);             // 81920
  short*          PfW1  = (short*)(ws + 368640);             // 20480 -> pad
  unsigned short* TAB   = (unsigned short*)(ws + 393216);    // N*160*2
  float*          HM    = (float*)(ws + 5472256);            // N*128*4
  unsigned short* POOLED= (unsigned short*)(ws + 13598720);  // N*128*2
  float*          RES   = (float*)(ws + 17661952);           // N*129*4
  int*            SORTED= (int*)(ws + 25851904);             // N*4

  scan_sort_kernel<<<1, 256, 2 * NSEG * sizeof(int), stream>>>(sizes, offs,
                                                               SORTED);
  pack_tab_kernel<<<(PACKV + TABV) / 256, 256, 0, stream>>>(
      interp, TAB, b0W1, b1W1, b0W2, b1W2, b0Wo, b1Wo, fW1,
      PB1, PB2, PWo, PW1m, PfW1);

  const size_t e_lds = 40960 + 32768 + 8 * 2 * 16 * 136 * 2;  // 143360

  // ---- block 0 ----
  hmprep_kernel<<<NTILE / 4, 256, 0, stream>>>(TAB, PW1m, b0b1, HM);
  edge_kernel<<<256, 512, e_lds, stream>>>(TAB, PB1, PB2, b0W1, HM, addInfo,
                                           nbrIdx, offs, SORTED, b0b2, POOLED);
  resout_kernel<1><<<NTILE / 4, 256, 0, stream>>>(
      POOLED, PWo, b0bo, interp, RES, TAB, PW1m + 20480, b1b1, HM,
      nullptr, nullptr, nullptr, nullptr, nullptr);

  // ---- block 1 ----
  edge_kernel<<<256, 512, e_lds, stream>>>(TAB, PB1 + 20480, PB2 + 16384, b1W1,
                                           HM, addInfo, nbrIdx, offs, SORTED,
                                           b1b2, POOLED);
  resout_kernel<0><<<NTILE / 4, 256, 0, stream>>>(
      POOLED, PWo + 18432, b1bo, RES, nullptr, nullptr, nullptr, nullptr,
      nullptr, PfW1, fb1, fW2, fb2, (float*)d_out);
}